// Round 1
// baseline (63.249 us; speedup 1.0000x reference)
//
#include <hip/hip_runtime.h>
#include <cstdint>
#include <cstddef>

// Dims (fixed by the reference)
#define R_   16
#define NH_  8
#define D_   32
#define C_   256
#define B_   16
#define XY_  1024      // 32*32
#define RH_  128       // R_*NH_
#define KD_  4096      // R_*NH_*D_
#define TP   32        // positions per block in main kernel
#define ZSTR 36        // padded LDS stride (floats), 16B aligned, breaks bank alias
#define LSTR 36

// ---------------------------------------------------------------------------
// Precompute: per (r,h) block computes
//   k[d] = Wk[r,h*D+d,:]·rims[r,:] + bk,   v[d] likewise
//   WLt[c][rh] = sum_d k[d]*Wq[rh*D+d, c]        (transposed for GEMM1 loads)
//   U[rh][c]   = sum_d v[d]*Wm[c, rh*D+d]
//   c0[rh]     = sum_d k[d]*bq[rh*D+d]
// ---------------------------------------------------------------------------
__global__ __launch_bounds__(256)
void rims_precompute(const float* __restrict__ rims,
                     const float* __restrict__ Wk,
                     const float* __restrict__ bk,
                     const float* __restrict__ Wv,
                     const float* __restrict__ bv,
                     const float* __restrict__ Wq,
                     const float* __restrict__ bq,
                     const float* __restrict__ Wm,
                     float* __restrict__ WLt,
                     float* __restrict__ Uo,
                     float* __restrict__ c0o)
{
    const int rh  = blockIdx.x;        // 0..127
    const int r   = rh >> 3;           // / NH_
    const int h   = rh & 7;
    const int tid = threadIdx.x;

    __shared__ float ks[D_];
    __shared__ float vs[D_];

    if (tid < 2 * D_) {
        const int d   = tid & (D_ - 1);
        const bool isv = (tid >= D_);
        const float* Wrow = (isv ? Wv : Wk) + ((size_t)r * 256 + h * D_ + d) * C_;
        const float* bias = (isv ? bv : bk);
        const float* rr   = rims + r * C_;
        float acc = 0.f;
        #pragma unroll 8
        for (int c = 0; c < C_; ++c) acc = fmaf(Wrow[c], rr[c], acc);
        acc += bias[r * 256 + h * D_ + d];
        if (isv) vs[d] = acc; else ks[d] = acc;
    }
    __syncthreads();

    const int c = tid;                 // 0..255
    float wl = 0.f, uu = 0.f;
    #pragma unroll
    for (int d = 0; d < D_; ++d) {
        wl = fmaf(ks[d], Wq[((size_t)rh * D_ + d) * C_ + c], wl);
        uu = fmaf(vs[d], Wm[(size_t)c * KD_ + rh * D_ + d], uu);
    }
    WLt[c * RH_ + rh] = wl;            // transposed layout [c][rh]
    Uo[rh * C_ + c]   = uu;            // row-major [rh][c]

    if (tid == 0) {
        float s = 0.f;
        #pragma unroll
        for (int d = 0; d < D_; ++d) s = fmaf(ks[d], bq[rh * D_ + d], s);
        c0o[rh] = s;
    }
}

// ---------------------------------------------------------------------------
// Main fused kernel: per block = 32 spatial positions of one batch image.
//   stage Z-tile (256 x 32) -> LDS
//   GEMM1: L[rh][p] = WLt[:,rh]·Zs[:,p] + c0[rh]          (128x32, K=256)
//   softmax over r (stride NH_ rows) per (h,p)
//   GEMM2: out[c][p] = U[rh][c]·A[rh][p] + bm[c]          (256x32, K=128)
// ---------------------------------------------------------------------------
__global__ __launch_bounds__(256, 2)
void rims_main(const float* __restrict__ z,
               const float* __restrict__ WLt,
               const float* __restrict__ Uo,
               const float* __restrict__ c0v,
               const float* __restrict__ bm,
               float* __restrict__ out)
{
    __shared__ float Zs[C_ * ZSTR];    // [c][p], padded stride
    __shared__ float Ls[RH_ * LSTR];   // [rh][p]

    const int tid = threadIdx.x;
    const int blk = blockIdx.x;        // 512 blocks total
    const int b   = blk >> 5;          // 32 blocks per batch image
    const int xy0 = (blk & 31) * TP;
    const float* zb = z + ((size_t)b * C_) * XY_ + xy0;

    // ---- stage Z tile (coalesced float4: 8 lanes cover 128B per c-row) ----
    {
        const int p4 = (tid & 7) << 2;
        const int cb = tid >> 3;       // 0..31
        #pragma unroll
        for (int i = 0; i < 8; ++i) {
            const int c = cb + (i << 5);
            const float4 v = *reinterpret_cast<const float4*>(zb + (size_t)c * XY_ + p4);
            *reinterpret_cast<float4*>(&Zs[c * ZSTR + p4]) = v;
        }
    }
    __syncthreads();

    // ---- GEMM1: thread computes 4rh x 4p tile over K=256 ----
    {
        const int p0  = (tid & 7) << 2;    // 0..28
        const int rh0 = (tid >> 3) << 2;   // 0..124
        float acc[4][4];
        #pragma unroll
        for (int j = 0; j < 4; ++j)
            #pragma unroll
            for (int i = 0; i < 4; ++i) acc[j][i] = 0.f;

        #pragma unroll 4
        for (int c = 0; c < C_; ++c) {
            const float4 wv = *reinterpret_cast<const float4*>(WLt + (c << 7) + rh0);
            const float4 zv = *reinterpret_cast<const float4*>(&Zs[c * ZSTR + p0]);
            const float wr[4] = {wv.x, wv.y, wv.z, wv.w};
            const float zr[4] = {zv.x, zv.y, zv.z, zv.w};
            #pragma unroll
            for (int j = 0; j < 4; ++j)
                #pragma unroll
                for (int i = 0; i < 4; ++i)
                    acc[j][i] = fmaf(wr[j], zr[i], acc[j][i]);
        }
        #pragma unroll
        for (int j = 0; j < 4; ++j) {
            const float cc = c0v[rh0 + j];
            float4 st;
            st.x = acc[j][0] + cc; st.y = acc[j][1] + cc;
            st.z = acc[j][2] + cc; st.w = acc[j][3] + cc;
            *reinterpret_cast<float4*>(&Ls[(rh0 + j) * LSTR + p0]) = st;
        }
    }
    __syncthreads();

    // ---- softmax over r (16 values, stride NH_ rows) per (h,p) ----
    {
        const int h = tid >> 5;        // 0..7
        const int p = tid & 31;        // 0..31
        float vals[R_];
        float m = -1e30f;
        #pragma unroll
        for (int r = 0; r < R_; ++r) {
            vals[r] = Ls[(r * NH_ + h) * LSTR + p];
            m = fmaxf(m, vals[r]);
        }
        float s = 0.f;
        #pragma unroll
        for (int r = 0; r < R_; ++r) { vals[r] = __expf(vals[r] - m); s += vals[r]; }
        const float inv = 1.f / s;
        #pragma unroll
        for (int r = 0; r < R_; ++r) Ls[(r * NH_ + h) * LSTR + p] = vals[r] * inv;
    }
    __syncthreads();

    // ---- GEMM2: thread computes 8c x 4p tile over K=128 ----
    {
        const int p0 = (tid & 7) << 2;     // 0..28
        const int cb = (tid >> 3) << 3;    // 0..248
        float acc[8][4];
        #pragma unroll
        for (int j = 0; j < 8; ++j)
            #pragma unroll
            for (int i = 0; i < 4; ++i) acc[j][i] = 0.f;

        #pragma unroll 2
        for (int rh = 0; rh < RH_; ++rh) {
            const float4 av = *reinterpret_cast<const float4*>(&Ls[rh * LSTR + p0]);
            const float4 u0 = *reinterpret_cast<const float4*>(Uo + (rh << 8) + cb);
            const float4 u1 = *reinterpret_cast<const float4*>(Uo + (rh << 8) + cb + 4);
            const float ar[4] = {av.x, av.y, av.z, av.w};
            const float ur[8] = {u0.x, u0.y, u0.z, u0.w, u1.x, u1.y, u1.z, u1.w};
            #pragma unroll
            for (int j = 0; j < 8; ++j)
                #pragma unroll
                for (int i = 0; i < 4; ++i)
                    acc[j][i] = fmaf(ur[j], ar[i], acc[j][i]);
        }

        float* ob = out + ((size_t)b * C_) * XY_ + xy0;
        #pragma unroll
        for (int j = 0; j < 8; ++j) {
            const float bb = bm[cb + j];
            float4 st;
            st.x = acc[j][0] + bb; st.y = acc[j][1] + bb;
            st.z = acc[j][2] + bb; st.w = acc[j][3] + bb;
            *reinterpret_cast<float4*>(ob + (size_t)(cb + j) * XY_ + p0) = st;
        }
    }
}

// ---------------------------------------------------------------------------
extern "C" void kernel_launch(void* const* d_in, const int* in_sizes, int n_in,
                              void* d_out, int out_size, void* d_ws, size_t ws_size,
                              hipStream_t stream)
{
    const float* z    = (const float*)d_in[0];
    const float* rims = (const float*)d_in[1];
    const float* Wk   = (const float*)d_in[2];
    const float* bk   = (const float*)d_in[3];
    const float* Wv   = (const float*)d_in[4];
    const float* bv   = (const float*)d_in[5];
    const float* Wq   = (const float*)d_in[6];
    const float* bq   = (const float*)d_in[7];
    const float* Wm   = (const float*)d_in[8];
    const float* bm   = (const float*)d_in[9];
    float* out = (float*)d_out;

    // workspace layout: WLt (C_*RH_) | U (RH_*C_) | c0 (RH_)  => ~257 KB
    float* WLt = (float*)d_ws;
    float* Uo  = WLt + C_ * RH_;
    float* c0o = Uo + RH_ * C_;

    rims_precompute<<<RH_, 256, 0, stream>>>(rims, Wk, bk, Wv, bv, Wq, bq, Wm,
                                             WLt, Uo, c0o);
    rims_main<<<(B_ * XY_) / TP, 256, 0, stream>>>(z, WLt, Uo, c0o, bm, out);
}